// Round 4
// baseline (278.762 us; speedup 1.0000x reference)
//
#include <hip/hip_runtime.h>

// GraphEmbedder: B=8, C=64, G=65536, 4 layers of y=lrelu(W@[x; x-x0]), then max over G.
// Identity: W@[x; x-x0] = Wa@x - Wb@x0, Wa = W[:,:64]+W[:,64:], Wb = W[:,64:].
// R11: DRAM-pattern round. R8/R10 inner-loop changes were null; hypothesis: the feature
// gather (short row-segments at 256KB row stride) caps the stream at ~1.7 TB/s (R9's
// fused kernel measured 1.49 TB/s on this exact pattern; harness fills prove 6.9 TB/s
// for dense access). Fix: block-cooperative staging -- each 128-col pass is read as
// dense 512B row-runs (2 rows x 512B per dwordx4 instruction) into a 33KB LDS tile;
// MFMA B-fragments are assembled from LDS with ds_read_b32 (2-way bank alias only =
// free). Weights stay resident in 128 VGPRs; bias/epilogue structure unchanged (proven).
// R9 lesson: no pointer-taking lambdas; macro compute; all indices static.

#define G_TOT 65536

typedef _Float16 hf2 __attribute__((ext_vector_type(2)));
typedef _Float16 hf4 __attribute__((ext_vector_type(4)));
typedef _Float16 hf8 __attribute__((ext_vector_type(8)));
typedef float float4_ __attribute__((ext_vector_type(4)));

static __device__ __forceinline__ hf2 pkh(float x, float y) {
    return __builtin_bit_cast(hf2, __builtin_amdgcn_cvt_pkrtz(x, y));
}

// ws layout (floats):
//   [0, 8192)       wf16: 16384 f16 weight fragments, frag-major
//                   elem (f*512 + lane*8 + e) = f16(Wa[l][16*mt+(lane&15)][32*pr+16*(e>>2)+4*(lane>>4)+(e&3)])
//                   with f = ((l*4+mt)*2+pr)
//   [16384, 18432)  nbias[b][l][o] fp32 (NEGATED bias)
//   [18432, 18944)  maxenc (uint32 ordered-float), zeroed by prep

__global__ __launch_bounds__(256) void ge_prep(
    const float* __restrict__ feat,
    const float* __restrict__ W0, const float* __restrict__ W1,
    const float* __restrict__ W2, const float* __restrict__ W3,
    float* __restrict__ ws)
{
    const int tid = threadIdx.x;
    const int blk = blockIdx.x;
    __shared__ float lw[64][129];
    __shared__ float x0[2][64];

    if (blk == 8) {
        // maxenc init + f16 fragment image of Wa = W[:,:64] + W[:,64:]
        unsigned* maxenc = (unsigned*)(ws + 18432);
        maxenc[tid] = 0u; maxenc[tid + 256] = 0u;
        _Float16* wf = (_Float16*)ws;
        for (int ci = tid; ci < 8192; ci += 256) {       // ci indexes hf2 chunks
            int f = ci >> 8, ln = (ci >> 2) & 63, h2 = ci & 3;
            int l = f >> 3, mt = (f >> 1) & 3, pr = f & 1;
            int o = (mt << 4) + (ln & 15);
            int c = (pr << 5) + ((h2 >> 1) << 4) + ((ln >> 4) << 2) + ((h2 & 1) << 1);
            const float* Wl = (l == 0) ? W0 : (l == 1) ? W1 : (l == 2) ? W2 : W3;
            float a0 = Wl[o * 128 + c]     + Wl[o * 128 + 64 + c];
            float a1 = Wl[o * 128 + c + 1] + Wl[o * 128 + 64 + c + 1];
            *(hf2*)&wf[ci << 1] = pkh(a0, a1);
        }
        return;
    }

    // blocks 0..7: exact fp32 bias chain for batch b = blk
    const int b = blk;
    if (tid < 64) x0[0][tid] = feat[(size_t)(b * 64 + tid) * G_TOT];
    float* nbias = ws + 16384;
    for (int l = 0; l < 4; ++l) {
        const float* Wl = (l == 0) ? W0 : (l == 1) ? W1 : (l == 2) ? W2 : W3;
        for (int i = tid; i < 64 * 128; i += 256) lw[i >> 7][i & 127] = Wl[i];
        __syncthreads();
        if (tid < 64) {
            const int o = tid;
            const float* src = x0[l & 1];
            float s1 = 0.f, s2 = 0.f;
            for (int c = 0; c < 64; ++c) {
                float xv = src[c];
                s1 += lw[o][c] * xv;
                s2 += lw[o][64 + c] * xv;
            }
            nbias[b * 256 + l * 64 + o] = -s2;          // negated, [b][l][o]
            x0[(l & 1) ^ 1][o] = fmaxf(s1, 0.1f * s1);
        }
        __syncthreads();
    }
}

// 4-layer MFMA chain on fragment array BF (hf4[4]); raw layer-3 max into rmax.
// Uses wfr, lbias, q, k01, rmax from enclosing scope. All indices static.
#define COMPUTE_TILE(BF)                                                              \
    _Pragma("unroll")                                                                 \
    for (int l = 0; l < 4; ++l) {                                                     \
        float4_ acc[4];                                                               \
        _Pragma("unroll")                                                             \
        for (int mt = 0; mt < 4; ++mt) {                                              \
            if (l < 3) acc[mt] = *(const float4_*)&lbias[(l << 6) + (mt << 4) + (q << 2)]; \
            else       acc[mt] = float4_{0.f, 0.f, 0.f, 0.f};                         \
        }                                                                             \
        _Pragma("unroll")                                                             \
        for (int mt = 0; mt < 4; ++mt) {                                              \
            _Pragma("unroll")                                                         \
            for (int pr = 0; pr < 2; ++pr) {                                          \
                union { hf8 h8; hf4 h4[2]; } ua;                                      \
                ua.h8 = wfr[l][mt][pr];                                               \
                acc[mt] = __builtin_amdgcn_mfma_f32_16x16x16f16(ua.h4[0], BF[(pr << 1) + 0], acc[mt], 0, 0, 0); \
                acc[mt] = __builtin_amdgcn_mfma_f32_16x16x16f16(ua.h4[1], BF[(pr << 1) + 1], acc[mt], 0, 0, 0); \
            }                                                                         \
        }                                                                             \
        if (l < 3) {                                                                  \
            _Pragma("unroll")                                                         \
            for (int mt = 0; mt < 4; ++mt) {                                          \
                union { hf2 h2[2]; hf4 h4; } u;                                       \
                u.h2[0] = pkh(acc[mt][0], acc[mt][1]);                                \
                u.h2[1] = pkh(acc[mt][2], acc[mt][3]);                                \
                hf4 h = u.h4;                                                         \
                h = __builtin_elementwise_max(h, h * k01);                            \
                BF[mt] = h;                                                           \
            }                                                                         \
        } else {                                                                      \
            _Pragma("unroll")                                                         \
            for (int mt = 0; mt < 4; ++mt)                                            \
                _Pragma("unroll")                                                     \
                for (int j = 0; j < 4; ++j)                                           \
                    rmax[mt][j] = fmaxf(rmax[mt][j], acc[mt][j]);                     \
        }                                                                             \
    }

__global__ __launch_bounds__(256, 2) void ge_main(
    const float* __restrict__ feat,
    const float* __restrict__ ws_wf,
    const float* __restrict__ nbias,
    unsigned* __restrict__ maxenc)
{
    // stg: one 128-col pass, row-major f32 [64 rows][132] (pad 4 -> frag reads 2-way only)
    __shared__ __align__(16) float stg[64][132];        // 33792 B
    __shared__ float lbias[256];
    __shared__ float blockmax[4][64];
    const int tid = threadIdx.x;
    const int b = blockIdx.x >> 6;      // 64 blocks per batch, 1024 cols each
    const int w = tid >> 6, lane = tid & 63, q = lane >> 4, n = lane & 15;

    // staging: wave w owns rows [16w, 16w+16); instr i reads rows 16w+2i+(lane>>5),
    // cols 4*(lane&31)..+3 of the pass -> two dense 512B row-runs per instruction
    const int srow = (w << 4) + (lane >> 5);
    const int scol = (lane & 31) << 2;
    const float* Sbase = feat + (size_t)b * 64 * G_TOT
                       + (size_t)((blockIdx.x & 63) << 10) + scol;

    // ---- issue pass-0 feature loads first (HBM latency hides under wfr/L2 reads) ----
    float4_ sbuf[8];
#pragma unroll
    for (int i = 0; i < 8; ++i)
        sbuf[i] = *(const float4_*)&Sbase[(size_t)(srow + (i << 1)) * G_TOT];

    // all 4 layers' weight fragments -> 128 VGPRs, read once (L2-broadcast 16 KB)
    hf8 wfr[4][4][2];
    {
        const hf8* wp = (const hf8*)ws_wf;
#pragma unroll
        for (int l = 0; l < 4; ++l)
#pragma unroll
            for (int mt = 0; mt < 4; ++mt)
#pragma unroll
                for (int pr = 0; pr < 2; ++pr)
                    wfr[l][mt][pr] = wp[((((((l << 2) + mt) << 1) + pr)) << 6) + lane];
    }

    lbias[tid] = nbias[(b << 8) + tid];

    float rmax[4][4];
#pragma unroll
    for (int mt = 0; mt < 4; ++mt)
#pragma unroll
        for (int j = 0; j < 4; ++j) rmax[mt][j] = -__builtin_inff();

    const hf4 k01 = { (_Float16)0.1f, (_Float16)0.1f, (_Float16)0.1f, (_Float16)0.1f };

    // ---- main loop: 8 passes of 128 cols; wave computes tiles 2w, 2w+1 each pass ----
#pragma unroll 1
    for (int p = 0; p < 8; ++p) {
        __syncthreads();            // prev-pass tile reads done (covers lbias at p==0)
#pragma unroll
        for (int i = 0; i < 8; ++i)
            *(float4_*)&stg[(w << 4) + (i << 1) + (lane >> 5)][scol] = sbuf[i];
        __syncthreads();
        if (p < 7) {                // issue next pass's loads; fly under this compute
            const float* Sp = Sbase + ((p + 1) << 7);
#pragma unroll
            for (int i = 0; i < 8; ++i)
                sbuf[i] = *(const float4_*)&Sp[(size_t)(srow + (i << 1)) * G_TOT];
        }
        {   // tile A: pass cols [32w, 32w+16)
            hf4 bfA[4];
#pragma unroll
            for (int kf = 0; kf < 4; ++kf) {
                float f0 = stg[(kf << 4) + (q << 2) + 0][(w << 5) + n];
                float f1 = stg[(kf << 4) + (q << 2) + 1][(w << 5) + n];
                float f2 = stg[(kf << 4) + (q << 2) + 2][(w << 5) + n];
                float f3 = stg[(kf << 4) + (q << 2) + 3][(w << 5) + n];
                union { hf2 h2[2]; hf4 h4; } u;
                u.h2[0] = pkh(f0, f1); u.h2[1] = pkh(f2, f3);
                bfA[kf] = u.h4;
            }
            COMPUTE_TILE(bfA)
        }
        {   // tile B: pass cols [32w+16, 32w+32)
            hf4 bfB[4];
#pragma unroll
            for (int kf = 0; kf < 4; ++kf) {
                float f0 = stg[(kf << 4) + (q << 2) + 0][(w << 5) + 16 + n];
                float f1 = stg[(kf << 4) + (q << 2) + 1][(w << 5) + 16 + n];
                float f2 = stg[(kf << 4) + (q << 2) + 2][(w << 5) + 16 + n];
                float f3 = stg[(kf << 4) + (q << 2) + 3][(w << 5) + 16 + n];
                union { hf2 h2[2]; hf4 h4; } u;
                u.h2[0] = pkh(f0, f1); u.h2[1] = pkh(f2, f3);
                bfB[kf] = u.h4;
            }
            COMPUTE_TILE(bfB)
        }
    }

    // ---- reduce raw max over 16 column-lanes ----
#pragma unroll
    for (int mt = 0; mt < 4; ++mt)
#pragma unroll
        for (int j = 0; j < 4; ++j) {
            float v = rmax[mt][j];
            v = fmaxf(v, __shfl_xor(v, 1, 64));
            v = fmaxf(v, __shfl_xor(v, 2, 64));
            v = fmaxf(v, __shfl_xor(v, 4, 64));
            v = fmaxf(v, __shfl_xor(v, 8, 64));
            rmax[mt][j] = v;
        }
    if (n == 0) {
#pragma unroll
        for (int mt = 0; mt < 4; ++mt)
#pragma unroll
            for (int j = 0; j < 4; ++j)
                blockmax[w][(mt << 4) + (q << 2) + j] = rmax[mt][j];
    }
    __syncthreads();
    if (tid < 64) {
        float v = fmaxf(fmaxf(blockmax[0][tid], blockmax[1][tid]),
                        fmaxf(blockmax[2][tid], blockmax[3][tid]));
        unsigned s = __float_as_uint(v);
        unsigned enc = (s & 0x80000000u) ? ~s : (s | 0x80000000u);
        atomicMax(&maxenc[b * 64 + tid], enc);
    }
}

__global__ void ge_final(const unsigned* __restrict__ maxenc,
                         const float* __restrict__ nbias,
                         float* __restrict__ out)
{
    int i = threadIdx.x;
    if (i < 512) {
        unsigned u = maxenc[i];
        unsigned s = (u & 0x80000000u) ? (u ^ 0x80000000u) : ~u;
        // deferred layer-3 bias + leaky-relu (both commute with max over G)
        float v = __uint_as_float(s) + nbias[((i >> 6) << 8) + 192 + (i & 63)];
        out[i] = fmaxf(v, 0.1f * v);
    }
}

extern "C" void kernel_launch(void* const* d_in, const int* in_sizes, int n_in,
                              void* d_out, int out_size, void* d_ws, size_t ws_size,
                              hipStream_t stream) {
    const float* feat = (const float*)d_in[0];
    const float* W0 = (const float*)d_in[1];
    const float* W1 = (const float*)d_in[2];
    const float* W2 = (const float*)d_in[3];
    const float* W3 = (const float*)d_in[4];
    float* ws = (float*)d_ws;
    unsigned* maxenc = (unsigned*)(ws + 18432);

    ge_prep<<<9, 256, 0, stream>>>(feat, W0, W1, W2, W3, ws);
    ge_main<<<512, 256, 0, stream>>>(feat, ws, ws + 16384, maxenc);
    ge_final<<<1, 512, 0, stream>>>(maxenc, ws + 16384, (float*)d_out);
}

// Round 5
// 263.176 us; speedup vs baseline: 1.0592x; 1.0592x over previous
//
#include <hip/hip_runtime.h>

// GraphEmbedder: B=8, C=64, G=65536, 4 layers of y=lrelu(W@[x; x-x0]), then max over G.
// Identity: W@[x; x-x0] = Wa@x - Wb@x0, Wa = W[:,:64]+W[:,64:], Wb = W[:,64:].
// R12 = R11's dense staging WITHOUT the register spill (R9/R11 lesson: >~128 live VGPRs
// => compiler spills to scratch, WRITE_SIZE 112MB, 127us):
//  - weights read per-tile from a 16KB LDS fragment image (R7-proven ds_read_b128
//    pattern, lane-contiguous 16B -> conflict-free) instead of 128 resident VGPRs
//  - features dense-staged per 128-col pass: 2 rows x 512B per dwordx4, 33KB LDS tile
//  - XCD-bijective block swizzle: nb = ((bid&7)<<6)|(bid>>3) -> each XCD's 64 resident
//    blocks cover ONE batch => full 256KB rows streamed per XCD L2, no cross-XCD dup
//  - regs ~105 (sbuf 32 + bf 8 + acc 16 + rmax 16 + misc) < 128 -> no scratch

#define G_TOT 65536

typedef _Float16 hf2 __attribute__((ext_vector_type(2)));
typedef _Float16 hf4 __attribute__((ext_vector_type(4)));
typedef _Float16 hf8 __attribute__((ext_vector_type(8)));
typedef float float4_ __attribute__((ext_vector_type(4)));

static __device__ __forceinline__ hf2 pkh(float x, float y) {
    return __builtin_bit_cast(hf2, __builtin_amdgcn_cvt_pkrtz(x, y));
}

// ws layout (floats):
//   [0, 8192)       wf16: 16384 f16 weight fragments, frag-major
//                   elem (f*512 + lane*8 + e) = f16(Wa[l][16*mt+(lane&15)][32*pr+16*(e>>2)+4*(lane>>4)+(e&3)])
//                   with f = ((l*4+mt)*2+pr)
//   [16384, 18432)  nbias[b][l][o] fp32 (NEGATED bias)
//   [18432, 18944)  maxenc (uint32 ordered-float), zeroed by prep

__global__ __launch_bounds__(256) void ge_prep(
    const float* __restrict__ feat,
    const float* __restrict__ W0, const float* __restrict__ W1,
    const float* __restrict__ W2, const float* __restrict__ W3,
    float* __restrict__ ws)
{
    const int tid = threadIdx.x;
    const int blk = blockIdx.x;
    __shared__ float lw[64][129];
    __shared__ float x0[2][64];

    if (blk == 8) {
        // maxenc init + f16 fragment image of Wa = W[:,:64] + W[:,64:]
        unsigned* maxenc = (unsigned*)(ws + 18432);
        maxenc[tid] = 0u; maxenc[tid + 256] = 0u;
        _Float16* wf = (_Float16*)ws;
        for (int ci = tid; ci < 8192; ci += 256) {       // ci indexes hf2 chunks
            int f = ci >> 8, ln = (ci >> 2) & 63, h2 = ci & 3;
            int l = f >> 3, mt = (f >> 1) & 3, pr = f & 1;
            int o = (mt << 4) + (ln & 15);
            int c = (pr << 5) + ((h2 >> 1) << 4) + ((ln >> 4) << 2) + ((h2 & 1) << 1);
            const float* Wl = (l == 0) ? W0 : (l == 1) ? W1 : (l == 2) ? W2 : W3;
            float a0 = Wl[o * 128 + c]     + Wl[o * 128 + 64 + c];
            float a1 = Wl[o * 128 + c + 1] + Wl[o * 128 + 64 + c + 1];
            *(hf2*)&wf[ci << 1] = pkh(a0, a1);
        }
        return;
    }

    // blocks 0..7: exact fp32 bias chain for batch b = blk
    const int b = blk;
    if (tid < 64) x0[0][tid] = feat[(size_t)(b * 64 + tid) * G_TOT];
    float* nbias = ws + 16384;
    for (int l = 0; l < 4; ++l) {
        const float* Wl = (l == 0) ? W0 : (l == 1) ? W1 : (l == 2) ? W2 : W3;
        for (int i = tid; i < 64 * 128; i += 256) lw[i >> 7][i & 127] = Wl[i];
        __syncthreads();
        if (tid < 64) {
            const int o = tid;
            const float* src = x0[l & 1];
            float s1 = 0.f, s2 = 0.f;
            for (int c = 0; c < 64; ++c) {
                float xv = src[c];
                s1 += lw[o][c] * xv;
                s2 += lw[o][64 + c] * xv;
            }
            nbias[b * 256 + l * 64 + o] = -s2;          // negated, [b][l][o]
            x0[(l & 1) ^ 1][o] = fmaxf(s1, 0.1f * s1);
        }
        __syncthreads();
    }
}

// 4-layer MFMA chain on fragment array BF (hf4[4]); weights from LDS image lwf;
// raw layer-3 max into rmax. Uses lwf, lbias, q, lane, k01, rmax from scope.
#define COMPUTE_TILE(BF)                                                              \
    _Pragma("unroll")                                                                 \
    for (int l = 0; l < 4; ++l) {                                                     \
        float4_ acc[4];                                                               \
        _Pragma("unroll")                                                             \
        for (int mt = 0; mt < 4; ++mt) {                                              \
            if (l < 3) acc[mt] = *(const float4_*)&lbias[(l << 6) + (mt << 4) + (q << 2)]; \
            else       acc[mt] = float4_{0.f, 0.f, 0.f, 0.f};                         \
        }                                                                             \
        _Pragma("unroll")                                                             \
        for (int mt = 0; mt < 4; ++mt) {                                              \
            _Pragma("unroll")                                                         \
            for (int pr = 0; pr < 2; ++pr) {                                          \
                union { hf8 h8; hf4 h4[2]; } ua;                                      \
                ua.h8 = *(const hf8*)&lwf[((((((l << 2) + mt) << 1) + pr) << 6) + lane) << 3]; \
                acc[mt] = __builtin_amdgcn_mfma_f32_16x16x16f16(ua.h4[0], BF[(pr << 1) + 0], acc[mt], 0, 0, 0); \
                acc[mt] = __builtin_amdgcn_mfma_f32_16x16x16f16(ua.h4[1], BF[(pr << 1) + 1], acc[mt], 0, 0, 0); \
            }                                                                         \
        }                                                                             \
        if (l < 3) {                                                                  \
            _Pragma("unroll")                                                         \
            for (int mt = 0; mt < 4; ++mt) {                                          \
                union { hf2 h2[2]; hf4 h4; } u;                                       \
                u.h2[0] = pkh(acc[mt][0], acc[mt][1]);                                \
                u.h2[1] = pkh(acc[mt][2], acc[mt][3]);                                \
                hf4 h = u.h4;                                                         \
                h = __builtin_elementwise_max(h, h * k01);                            \
                BF[mt] = h;                                                           \
            }                                                                         \
        } else {                                                                      \
            _Pragma("unroll")                                                         \
            for (int mt = 0; mt < 4; ++mt)                                            \
                _Pragma("unroll")                                                     \
                for (int j = 0; j < 4; ++j)                                           \
                    rmax[mt][j] = fmaxf(rmax[mt][j], acc[mt][j]);                     \
        }                                                                             \
    }

__global__ __launch_bounds__(256, 2) void ge_main(
    const float* __restrict__ feat,
    const float* __restrict__ ws_wf,
    const float* __restrict__ nbias,
    unsigned* __restrict__ maxenc)
{
    // stg: one 128-col pass, row-major f32 [64][132] (pad -> frag reads low-conflict)
    __shared__ __align__(16) float stg[64][132];        // 33792 B
    __shared__ __align__(16) _Float16 lwf[16384];       // 32768 B weight fragment image
    __shared__ float lbias[256];
    __shared__ float blockmax[4][64];
    const int tid = threadIdx.x;

    // XCD-bijective swizzle: 512 blocks, xcd = bid&7 (round-robin HW assignment),
    // nb = xcd*64 + slot -> each XCD's 64 resident blocks cover exactly one batch.
    const int nb = ((blockIdx.x & 7) << 6) | (blockIdx.x >> 3);
    const int b = nb >> 6;              // batch
    const int w = tid >> 6, lane = tid & 63, q = lane >> 4, n = lane & 15;

    // staging: wave w owns rows [16w,16w+16); instr i covers rows 16w+2i+(lane>>5),
    // cols 4*(lane&31) of the pass -> two dense 512B row-runs per dwordx4
    const int srow = (w << 4) + (lane >> 5);
    const int scol = (lane & 31) << 2;
    const float* Sbase = feat + (size_t)b * 64 * G_TOT
                       + (size_t)((nb & 63) << 10) + scol;

    // ---- issue pass-0 feature loads first (fly under weight/L2 staging) ----
    float4_ sbuf[8];
#pragma unroll
    for (int i = 0; i < 8; ++i)
        sbuf[i] = *(const float4_*)&Sbase[(size_t)(srow + (i << 1)) * G_TOT];

    // stage weight fragment image (32 KB) + bias into LDS
    {
        const float4_* wp = (const float4_*)ws_wf;
#pragma unroll
        for (int i = 0; i < 8; ++i)
            *(float4_*)&lwf[(tid + (i << 8)) << 3] = wp[tid + (i << 8)];
    }
    lbias[tid] = nbias[(b << 8) + tid];

    float rmax[4][4];
#pragma unroll
    for (int mt = 0; mt < 4; ++mt)
#pragma unroll
        for (int j = 0; j < 4; ++j) rmax[mt][j] = -__builtin_inff();

    const hf4 k01 = { (_Float16)0.1f, (_Float16)0.1f, (_Float16)0.1f, (_Float16)0.1f };

    __syncthreads();   // lwf + lbias visible

    // ---- main loop: 8 passes of 128 cols; wave computes tiles 2w, 2w+1 each pass ----
#pragma unroll 1
    for (int p = 0; p < 8; ++p) {
#pragma unroll
        for (int i = 0; i < 8; ++i)     // waits on pass-p loads
            *(float4_*)&stg[(w << 4) + (i << 1) + (lane >> 5)][scol] = sbuf[i];
        __syncthreads();
        if (p < 7) {                    // issue next pass's loads; fly under compute
            const float* Sp = Sbase + ((p + 1) << 7);
#pragma unroll
            for (int i = 0; i < 8; ++i)
                sbuf[i] = *(const float4_*)&Sp[(size_t)(srow + (i << 1)) * G_TOT];
        }
        {   // tile A: pass cols [32w, 32w+16)
            hf4 bfA[4];
#pragma unroll
            for (int kf = 0; kf < 4; ++kf) {
                float f0 = stg[(kf << 4) + (q << 2) + 0][(w << 5) + n];
                float f1 = stg[(kf << 4) + (q << 2) + 1][(w << 5) + n];
                float f2 = stg[(kf << 4) + (q << 2) + 2][(w << 5) + n];
                float f3 = stg[(kf << 4) + (q << 2) + 3][(w << 5) + n];
                union { hf2 h2[2]; hf4 h4; } u;
                u.h2[0] = pkh(f0, f1); u.h2[1] = pkh(f2, f3);
                bfA[kf] = u.h4;
            }
            COMPUTE_TILE(bfA)
        }
        {   // tile B: pass cols [32w+16, 32w+32)
            hf4 bfB[4];
#pragma unroll
            for (int kf = 0; kf < 4; ++kf) {
                float f0 = stg[(kf << 4) + (q << 2) + 0][(w << 5) + 16 + n];
                float f1 = stg[(kf << 4) + (q << 2) + 1][(w << 5) + 16 + n];
                float f2 = stg[(kf << 4) + (q << 2) + 2][(w << 5) + 16 + n];
                float f3 = stg[(kf << 4) + (q << 2) + 3][(w << 5) + 16 + n];
                union { hf2 h2[2]; hf4 h4; } u;
                u.h2[0] = pkh(f0, f1); u.h2[1] = pkh(f2, f3);
                bfB[kf] = u.h4;
            }
            COMPUTE_TILE(bfB)
        }
        __syncthreads();                // tile reads done before next pass overwrites stg
    }

    // ---- reduce raw max over 16 column-lanes ----
#pragma unroll
    for (int mt = 0; mt < 4; ++mt)
#pragma unroll
        for (int j = 0; j < 4; ++j) {
            float v = rmax[mt][j];
            v = fmaxf(v, __shfl_xor(v, 1, 64));
            v = fmaxf(v, __shfl_xor(v, 2, 64));
            v = fmaxf(v, __shfl_xor(v, 4, 64));
            v = fmaxf(v, __shfl_xor(v, 8, 64));
            rmax[mt][j] = v;
        }
    if (n == 0) {
#pragma unroll
        for (int mt = 0; mt < 4; ++mt)
#pragma unroll
            for (int j = 0; j < 4; ++j)
                blockmax[w][(mt << 4) + (q << 2) + j] = rmax[mt][j];
    }
    __syncthreads();
    if (tid < 64) {
        float v = fmaxf(fmaxf(blockmax[0][tid], blockmax[1][tid]),
                        fmaxf(blockmax[2][tid], blockmax[3][tid]));
        unsigned s = __float_as_uint(v);
        unsigned enc = (s & 0x80000000u) ? ~s : (s | 0x80000000u);
        atomicMax(&maxenc[b * 64 + tid], enc);
    }
}

__global__ void ge_final(const unsigned* __restrict__ maxenc,
                         const float* __restrict__ nbias,
                         float* __restrict__ out)
{
    int i = threadIdx.x;
    if (i < 512) {
        unsigned u = maxenc[i];
        unsigned s = (u & 0x80000000u) ? (u ^ 0x80000000u) : ~u;
        // deferred layer-3 bias + leaky-relu (both commute with max over G)
        float v = __uint_as_float(s) + nbias[((i >> 6) << 8) + 192 + (i & 63)];
        out[i] = fmaxf(v, 0.1f * v);
    }
}

extern "C" void kernel_launch(void* const* d_in, const int* in_sizes, int n_in,
                              void* d_out, int out_size, void* d_ws, size_t ws_size,
                              hipStream_t stream) {
    const float* feat = (const float*)d_in[0];
    const float* W0 = (const float*)d_in[1];
    const float* W1 = (const float*)d_in[2];
    const float* W2 = (const float*)d_in[3];
    const float* W3 = (const float*)d_in[4];
    float* ws = (float*)d_ws;
    unsigned* maxenc = (unsigned*)(ws + 18432);

    ge_prep<<<9, 256, 0, stream>>>(feat, W0, W1, W2, W3, ws);
    ge_main<<<512, 256, 0, stream>>>(feat, ws, ws + 16384, maxenc);
    ge_final<<<1, 512, 0, stream>>>(maxenc, ws + 16384, (float*)d_out);
}

// Round 6
// 219.862 us; speedup vs baseline: 1.2679x; 1.1970x over previous
//
#include <hip/hip_runtime.h>

// GraphEmbedder: B=8, C=64, G=65536, 4 layers of y=lrelu(W@[x; x-x0]), then max over G.
// Identity: W@[x; x-x0] = Wa@x - Wb@x0, Wa = W[:,:64]+W[:,64:], Wb = W[:,64:].
// R13: spill-proof dense staging. R9/R11/R12 all hit the same failure: big __shared__
// tile + register prefetch buffer => compiler caps at 128 VGPR and spills (WRITE_SIZE
// 23-112 MB, ge_main 110-127us). Clean ge_main back-solves to ~65us = 2.0 TB/s gather.
// This round:
//  - features staged global->LDS via __builtin_amdgcn_global_load_lds width=16: ZERO
//    staging registers, async (flies across the pass), dense 4-row x 256B runs/instr
//  - LDS group layout: 16 groups of 4 rows x 64 cols (1024B) + 64B pad -> linear dest
//    (HW writes base+lane*16) AND 2-way-only bank alias on fragment ds_read_b32 (free)
//  - weights from 16KB LDS fragment image (R7-proven b128 read), regs ~80 << 128
//  - double-buffered, 1 barrier/pass; compiler's vmcnt-drain@barrier = consumer wait
//  - XCD-bijective swizzle kept (R12: FETCH 141->94 MB)

#define G_TOT 65536

typedef _Float16 hf2 __attribute__((ext_vector_type(2)));
typedef _Float16 hf4 __attribute__((ext_vector_type(4)));
typedef _Float16 hf8 __attribute__((ext_vector_type(8)));
typedef float float4_ __attribute__((ext_vector_type(4)));

static __device__ __forceinline__ hf2 pkh(float x, float y) {
    return __builtin_bit_cast(hf2, __builtin_amdgcn_cvt_pkrtz(x, y));
}

// ws layout (floats):
//   [0, 8192)       wf16: 16384 f16 weight fragments, frag-major
//                   elem (f*512 + lane*8 + e) = f16(Wa[l][16*mt+(lane&15)][32*pr+16*(e>>2)+4*(lane>>4)+(e&3)])
//                   with f = ((l*4+mt)*2+pr)
//   [16384, 18432)  nbias[b][l][o] fp32 (NEGATED bias)
//   [18432, 18944)  maxenc (uint32 ordered-float), zeroed by prep

__global__ __launch_bounds__(256) void ge_prep(
    const float* __restrict__ feat,
    const float* __restrict__ W0, const float* __restrict__ W1,
    const float* __restrict__ W2, const float* __restrict__ W3,
    float* __restrict__ ws)
{
    const int tid = threadIdx.x;
    const int blk = blockIdx.x;
    __shared__ float lw[64][129];
    __shared__ float x0[2][64];

    if (blk == 8) {
        // maxenc init + f16 fragment image of Wa = W[:,:64] + W[:,64:]
        unsigned* maxenc = (unsigned*)(ws + 18432);
        maxenc[tid] = 0u; maxenc[tid + 256] = 0u;
        _Float16* wf = (_Float16*)ws;
        for (int ci = tid; ci < 8192; ci += 256) {       // ci indexes hf2 chunks
            int f = ci >> 8, ln = (ci >> 2) & 63, h2 = ci & 3;
            int l = f >> 3, mt = (f >> 1) & 3, pr = f & 1;
            int o = (mt << 4) + (ln & 15);
            int c = (pr << 5) + ((h2 >> 1) << 4) + ((ln >> 4) << 2) + ((h2 & 1) << 1);
            const float* Wl = (l == 0) ? W0 : (l == 1) ? W1 : (l == 2) ? W2 : W3;
            float a0 = Wl[o * 128 + c]     + Wl[o * 128 + 64 + c];
            float a1 = Wl[o * 128 + c + 1] + Wl[o * 128 + 64 + c + 1];
            *(hf2*)&wf[ci << 1] = pkh(a0, a1);
        }
        return;
    }

    // blocks 0..7: exact fp32 bias chain for batch b = blk
    const int b = blk;
    if (tid < 64) x0[0][tid] = feat[(size_t)(b * 64 + tid) * G_TOT];
    float* nbias = ws + 16384;
    for (int l = 0; l < 4; ++l) {
        const float* Wl = (l == 0) ? W0 : (l == 1) ? W1 : (l == 2) ? W2 : W3;
        for (int i = tid; i < 64 * 128; i += 256) lw[i >> 7][i & 127] = Wl[i];
        __syncthreads();
        if (tid < 64) {
            const int o = tid;
            const float* src = x0[l & 1];
            float s1 = 0.f, s2 = 0.f;
            for (int c = 0; c < 64; ++c) {
                float xv = src[c];
                s1 += lw[o][c] * xv;
                s2 += lw[o][64 + c] * xv;
            }
            nbias[b * 256 + l * 64 + o] = -s2;          // negated, [b][l][o]
            x0[(l & 1) ^ 1][o] = fmaxf(s1, 0.1f * s1);
        }
        __syncthreads();
    }
}

// 4-layer MFMA chain on fragment array BF (hf4[4]); weights from LDS image lwf;
// raw layer-3 max into rmax. Uses lwf, lbias, q, lane, k01, rmax from scope.
#define COMPUTE_TILE(BF)                                                              \
    _Pragma("unroll")                                                                 \
    for (int l = 0; l < 4; ++l) {                                                     \
        float4_ acc[4];                                                               \
        _Pragma("unroll")                                                             \
        for (int mt = 0; mt < 4; ++mt) {                                              \
            if (l < 3) acc[mt] = *(const float4_*)&lbias[(l << 6) + (mt << 4) + (q << 2)]; \
            else       acc[mt] = float4_{0.f, 0.f, 0.f, 0.f};                         \
        }                                                                             \
        _Pragma("unroll")                                                             \
        for (int mt = 0; mt < 4; ++mt) {                                              \
            _Pragma("unroll")                                                         \
            for (int pr = 0; pr < 2; ++pr) {                                          \
                union { hf8 h8; hf4 h4[2]; } ua;                                      \
                ua.h8 = *(const hf8*)&lwf[((((((l << 2) + mt) << 1) + pr) << 6) + lane) << 3]; \
                acc[mt] = __builtin_amdgcn_mfma_f32_16x16x16f16(ua.h4[0], BF[(pr << 1) + 0], acc[mt], 0, 0, 0); \
                acc[mt] = __builtin_amdgcn_mfma_f32_16x16x16f16(ua.h4[1], BF[(pr << 1) + 1], acc[mt], 0, 0, 0); \
            }                                                                         \
        }                                                                             \
        if (l < 3) {                                                                  \
            _Pragma("unroll")                                                         \
            for (int mt = 0; mt < 4; ++mt) {                                          \
                union { hf2 h2[2]; hf4 h4; } u;                                       \
                u.h2[0] = pkh(acc[mt][0], acc[mt][1]);                                \
                u.h2[1] = pkh(acc[mt][2], acc[mt][3]);                                \
                hf4 h = u.h4;                                                         \
                h = __builtin_elementwise_max(h, h * k01);                            \
                BF[mt] = h;                                                           \
            }                                                                         \
        } else {                                                                      \
            _Pragma("unroll")                                                         \
            for (int mt = 0; mt < 4; ++mt)                                            \
                _Pragma("unroll")                                                     \
                for (int j = 0; j < 4; ++j)                                           \
                    rmax[mt][j] = fmaxf(rmax[mt][j], acc[mt][j]);                     \
        }                                                                             \
    }

// stage one 64-col pass into LDS buffer at float-offset BUFBASE (0 or 4352):
// instr j stages group G=(w<<2)+j = rows 4G..4G+3 x 64 cols as a linear 1KB block
// (HW: dst_base + lane*16; lane's 16B = row 4G+(lane>>4), cols 4*(lane&15)..+3).
// Global src is per-lane: dense 256B run per row. PCOL = pass column offset (floats).
#define STAGE(PCOL, BUFBASE)                                                          \
    _Pragma("unroll")                                                                 \
    for (int j = 0; j < 4; ++j) {                                                     \
        const int G_ = (w << 2) + j;                                                  \
        const float* src_ = Fbase + (size_t)((G_ << 2) + (lane >> 4)) * G_TOT         \
                          + (PCOL) + ((lane & 15) << 2);                              \
        __builtin_amdgcn_global_load_lds(                                             \
            (const __attribute__((address_space(1))) unsigned*)src_,                  \
            (__attribute__((address_space(3))) unsigned*)&stg[(BUFBASE) + G_ * 272],  \
            16, 0, 0);                                                                \
    }

__global__ __launch_bounds__(256, 2) void ge_main(
    const float* __restrict__ feat,
    const float* __restrict__ ws_wf,
    const float* __restrict__ nbias,
    unsigned* __restrict__ maxenc)
{
    // 2 buffers x 16 groups x (4 rows x 64 cols + 16 floats pad) = 34816 B
    __shared__ __align__(16) float stg[2 * 16 * 272];
    __shared__ __align__(16) _Float16 lwf[16384];       // 32768 B weight fragment image
    __shared__ float lbias[256];
    __shared__ float blockmax[4][64];
    const int tid = threadIdx.x;

    // XCD-bijective swizzle: each XCD's 64 resident blocks cover exactly one batch
    const int nb = ((blockIdx.x & 7) << 6) | (blockIdx.x >> 3);
    const int b = nb >> 6;
    const int w = tid >> 6, lane = tid & 63, q = lane >> 4, n = lane & 15;

    const float* Fbase = feat + (size_t)b * 64 * G_TOT + (size_t)((nb & 63) << 10);

    // ---- prologue: issue pass-0 stage (async), then weights+bias into LDS ----
    STAGE(0, 0)
    {
        const float4_* wp = (const float4_*)ws_wf;
#pragma unroll
        for (int i = 0; i < 8; ++i)
            *(float4_*)&lwf[(tid + (i << 8)) << 3] = wp[tid + (i << 8)];
    }
    lbias[tid] = nbias[(b << 8) + tid];

    float rmax[4][4];
#pragma unroll
    for (int mt = 0; mt < 4; ++mt)
#pragma unroll
        for (int j = 0; j < 4; ++j) rmax[mt][j] = -__builtin_inff();

    const hf4 k01 = { (_Float16)0.1f, (_Float16)0.1f, (_Float16)0.1f, (_Float16)0.1f };

    // ---- main loop: 16 passes of 64 cols; wave w computes cols 16w..16w+15 ----
    int curbase = 0;
#pragma unroll 1
    for (int p = 0; p < 16; ++p) {
        __syncthreads();            // drains vmcnt -> buf[cur] staged by ALL waves
        if (p < 15) { STAGE((p + 1) << 6, curbase ^ 4352) }
        // feature fragments: rows 16kf+4q+r (group 4kf+q, row r), col 16w+n
        hf4 bf[4];
#pragma unroll
        for (int kf = 0; kf < 4; ++kf) {
            const int gb = curbase + ((kf << 2) + q) * 272 + (w << 4) + n;
            float f0 = stg[gb];
            float f1 = stg[gb + 64];
            float f2 = stg[gb + 128];
            float f3 = stg[gb + 192];
            union { hf2 h2[2]; hf4 h4; } u;
            u.h2[0] = pkh(f0, f1); u.h2[1] = pkh(f2, f3);
            bf[kf] = u.h4;
        }
        COMPUTE_TILE(bf)
        curbase ^= 4352;
    }

    // ---- reduce raw max over 16 column-lanes ----
#pragma unroll
    for (int mt = 0; mt < 4; ++mt)
#pragma unroll
        for (int j = 0; j < 4; ++j) {
            float v = rmax[mt][j];
            v = fmaxf(v, __shfl_xor(v, 1, 64));
            v = fmaxf(v, __shfl_xor(v, 2, 64));
            v = fmaxf(v, __shfl_xor(v, 4, 64));
            v = fmaxf(v, __shfl_xor(v, 8, 64));
            rmax[mt][j] = v;
        }
    if (n == 0) {
#pragma unroll
        for (int mt = 0; mt < 4; ++mt)
#pragma unroll
            for (int j = 0; j < 4; ++j)
                blockmax[w][(mt << 4) + (q << 2) + j] = rmax[mt][j];
    }
    __syncthreads();
    if (tid < 64) {
        float v = fmaxf(fmaxf(blockmax[0][tid], blockmax[1][tid]),
                        fmaxf(blockmax[2][tid], blockmax[3][tid]));
        unsigned s = __float_as_uint(v);
        unsigned enc = (s & 0x80000000u) ? ~s : (s | 0x80000000u);
        atomicMax(&maxenc[b * 64 + tid], enc);
    }
}

__global__ void ge_final(const unsigned* __restrict__ maxenc,
                         const float* __restrict__ nbias,
                         float* __restrict__ out)
{
    int i = threadIdx.x;
    if (i < 512) {
        unsigned u = maxenc[i];
        unsigned s = (u & 0x80000000u) ? (u ^ 0x80000000u) : ~u;
        // deferred layer-3 bias + leaky-relu (both commute with max over G)
        float v = __uint_as_float(s) + nbias[((i >> 6) << 8) + 192 + (i & 63)];
        out[i] = fmaxf(v, 0.1f * v);
    }
}

extern "C" void kernel_launch(void* const* d_in, const int* in_sizes, int n_in,
                              void* d_out, int out_size, void* d_ws, size_t ws_size,
                              hipStream_t stream) {
    const float* feat = (const float*)d_in[0];
    const float* W0 = (const float*)d_in[1];
    const float* W1 = (const float*)d_in[2];
    const float* W2 = (const float*)d_in[3];
    const float* W3 = (const float*)d_in[4];
    float* ws = (float*)d_ws;
    unsigned* maxenc = (unsigned*)(ws + 18432);

    ge_prep<<<9, 256, 0, stream>>>(feat, W0, W1, W2, W3, ws);
    ge_main<<<512, 256, 0, stream>>>(feat, ws, ws + 16384, maxenc);
    ge_final<<<1, 512, 0, stream>>>(maxenc, ws + 16384, (float*)d_out);
}